// Round 1
// baseline (657.117 us; speedup 1.0000x reference)
//
#include <hip/hip_runtime.h>

// Problem constants
#define BB 8
#define CIN 32
#define COUT 32
#define DD 16
#define HH 64
#define WW 64
#define EE 8

// Workspace layout (floats)
#define WSUM_OFF 0      // [c][o][28] : 32*32*28 = 28672 (27 taps + 1 pad)
#define BIAS_OFF 28672  // [32]
#define RW_OFF   28704  // [8]

#define CSPLIT 16
#define ROWLEN 68       // 66 real cols (x=-1..64) + 2 pad, keeps float4 alignment

// ---------------------------------------------------------------------------
// Prep: Wsum[c][o][k] = sum_e weight[e,o,c,k]; bias_sum[o]; rw_sum[b]
// ---------------------------------------------------------------------------
__global__ void condconv_prep(const float* __restrict__ rw,      // [B,E]
                              const float* __restrict__ weight,  // [E,O,C,27]
                              const float* __restrict__ bias,    // [E,O]
                              float* __restrict__ ws) {
    int t = blockIdx.x * blockDim.x + threadIdx.x;
    if (t < 27648) {
        int oc = t / 27;
        int k  = t - oc * 27;
        int o  = oc & 31;
        int c  = oc >> 5;
        int src = o * 864 + c * 27 + k;   // within one expert: o*C*27 + c*27 + k
        float s = 0.f;
#pragma unroll
        for (int e = 0; e < EE; ++e) s += weight[e * 27648 + src];
        ws[WSUM_OFF + (c * 32 + o) * 28 + k] = s;
    } else if (t < 27680) {
        int o = t - 27648;
        float s = 0.f;
#pragma unroll
        for (int e = 0; e < EE; ++e) s += bias[e * 32 + o];
        ws[BIAS_OFF + o] = s;
    } else if (t < 27688) {
        int b = t - 27680;
        float s = 0.f;
#pragma unroll
        for (int i = 0; i < EE; ++i) s += rw[b * 8 + i];
        ws[RW_OFF + b] = s;
    }
}

// ---------------------------------------------------------------------------
// Conv: one block per (b, z, y). 256 threads = (tx:16, ty:16).
// Thread computes 4 consecutive x positions for o = ty and o = ty+16.
// Input tile (16 channels x 3 z-planes x 3 rows x 68 cols) staged in LDS,
// two phases of 16 channels each.
// ---------------------------------------------------------------------------
__global__ __launch_bounds__(256) void condconv_conv(
        const float* __restrict__ x,   // [B,C,D,H,W]
        const float* __restrict__ ws,
        float* __restrict__ out) {     // [B,O,D,H,W]
    __shared__ float tile[CSPLIT * 9 * ROWLEN];  // 9792 floats = 39168 B

    const int tx = threadIdx.x;   // 0..15
    const int ty = threadIdx.y;   // 0..15
    const int y  = blockIdx.x;    // 0..63
    const int z  = blockIdx.y;    // 0..15
    const int b  = blockIdx.z;    // 0..7
    const int tid = ty * 16 + tx;

    const int o0 = ty;
    const int o1 = ty + 16;

    float acc0[4] = {0.f, 0.f, 0.f, 0.f};
    float acc1[4] = {0.f, 0.f, 0.f, 0.f};

    for (int phase = 0; phase < 2; ++phase) {
        const int cbase = phase * CSPLIT;

        __syncthreads();  // phase 1: protect previous-phase reads before overwrite
        // ---- stage 16 channels into LDS ----
        for (int i = tid; i < CSPLIT * 9 * ROWLEN; i += 256) {
            int row = i / ROWLEN;
            int col = i - row * ROWLEN;        // 0..67 ; col-1 = x coordinate
            int cc  = row / 9;
            int r9  = row - cc * 9;
            int dz  = r9 / 3;
            int dy  = r9 - dz * 3;
            int gz  = z + dz - 1;
            int gy  = y + dy - 1;
            float v = 0.f;
            if (gz >= 0 && gz < DD && gy >= 0 && gy < HH && col >= 1 && col <= WW) {
                v = x[(((size_t)(b * CIN + (cbase + cc)) * DD + gz) * HH + gy) * WW
                      + (col - 1)];
            }
            tile[i] = v;
        }
        __syncthreads();

        // ---- compute ----
        for (int c = 0; c < CSPLIT; ++c) {
            const float* wp0 = ws + WSUM_OFF + ((cbase + c) * 32 + o0) * 28;
            const float* wp1 = ws + WSUM_OFF + ((cbase + c) * 32 + o1) * 28;
            float w0[28], w1[28];
#pragma unroll
            for (int q = 0; q < 7; ++q) {
                *(float4*)&w0[q * 4] = ((const float4*)wp0)[q];
                *(float4*)&w1[q * 4] = ((const float4*)wp1)[q];
            }
#pragma unroll
            for (int dz = 0; dz < 3; ++dz) {
#pragma unroll
                for (int dy = 0; dy < 3; ++dy) {
                    const float* lp = &tile[(c * 9 + dz * 3 + dy) * ROWLEN + 4 * tx];
                    float4 xa = *(const float4*)lp;        // x-1 .. x+2
                    float4 xb = *(const float4*)(lp + 4);  // x+3 .. x+6 (2 unused)
                    float v[8] = {xa.x, xa.y, xa.z, xa.w, xb.x, xb.y, xb.z, xb.w};
                    const int kb = dz * 9 + dy * 3;
#pragma unroll
                    for (int kw = 0; kw < 3; ++kw) {
                        float wa = w0[kb + kw];
                        float wb = w1[kb + kw];
#pragma unroll
                        for (int xi = 0; xi < 4; ++xi) {
                            acc0[xi] += wa * v[xi + kw];
                            acc1[xi] += wb * v[xi + kw];
                        }
                    }
                }
            }
        }
    }

    const float rwb = ws[RW_OFF + b];
    const float bs0 = ws[BIAS_OFF + o0];
    const float bs1 = ws[BIAS_OFF + o1];

    float4 r0, r1;
    r0.x = rwb * (acc0[0] + bs0);
    r0.y = rwb * (acc0[1] + bs0);
    r0.z = rwb * (acc0[2] + bs0);
    r0.w = rwb * (acc0[3] + bs0);
    r1.x = rwb * (acc1[0] + bs1);
    r1.y = rwb * (acc1[1] + bs1);
    r1.z = rwb * (acc1[2] + bs1);
    r1.w = rwb * (acc1[3] + bs1);

    size_t ob0 = (((size_t)(b * COUT + o0) * DD + z) * HH + y) * WW + 4 * tx;
    size_t ob1 = (((size_t)(b * COUT + o1) * DD + z) * HH + y) * WW + 4 * tx;
    *(float4*)&out[ob0] = r0;
    *(float4*)&out[ob1] = r1;
}

// ---------------------------------------------------------------------------
extern "C" void kernel_launch(void* const* d_in, const int* in_sizes, int n_in,
                              void* d_out, int out_size, void* d_ws, size_t ws_size,
                              hipStream_t stream) {
    const float* x      = (const float*)d_in[0];  // [8,32,16,64,64]
    const float* rw     = (const float*)d_in[1];  // [8,8]
    const float* weight = (const float*)d_in[2];  // [8,32,32,3,3,3]
    const float* bias   = (const float*)d_in[3];  // [8,32]
    float* out = (float*)d_out;
    float* ws  = (float*)d_ws;

    condconv_prep<<<dim3((27688 + 255) / 256), dim3(256), 0, stream>>>(rw, weight, bias, ws);

    dim3 grid(HH, DD, BB);   // (y, z, b)
    dim3 block(16, 16);
    condconv_conv<<<grid, block, 0, stream>>>(x, ws, out);
}

// Round 2
// 156.296 us; speedup vs baseline: 4.2043x; 4.2043x over previous
//
#include <hip/hip_runtime.h>

typedef short short8 __attribute__((ext_vector_type(8)));
typedef float f32x4 __attribute__((ext_vector_type(4)));

// Workspace byte offsets
#define XT_OFF  0u           // bf16 xT[b][z][y][x][c] : 8*16*64*64*32*2 = 33554432 B
#define WF_OFF  33554432u    // bf16 wfrag[t=27][ot=2][lane=64][j=8] = 55296 B
#define RWB_OFF 33609728u    // f32 rw_sum[b]*bias_sum[o] : [8][32] = 1024 B
#define RWS_OFF 33610752u    // f32 rw_sum[8] = 32 B

__device__ __forceinline__ unsigned bf16rne(float f) {
    unsigned u = __float_as_uint(f);
    return (u + 0x7FFFu + ((u >> 16) & 1u)) >> 16;
}

// ---------------------------------------------------------------------------
// Prep: wfrag in MFMA A-operand layout; rwb_bias; rw_sum.
// A-frag (16x16x32 bf16): lane l holds A[m = l&15][k = 8*(l>>4)+j], j=0..7.
// Here m = o (within o-tile), k = c.  wfrag elem idx = ((t*2+ot)*64 + l)*8 + j.
// ---------------------------------------------------------------------------
__global__ void condconv_prep(const float* __restrict__ rw,      // [8,8]
                              const float* __restrict__ weight,  // [8,32,32,27]
                              const float* __restrict__ bias,    // [8,32]
                              char* __restrict__ ws) {
    int i = blockIdx.x * 256 + threadIdx.x;
    if (i < 27648) {
        int t   = i >> 10;
        int rem = i & 1023;
        int ot  = rem >> 9;
        int l   = (rem >> 3) & 63;
        int j   = rem & 7;
        int o   = ot * 16 + (l & 15);
        int c   = 8 * (l >> 4) + j;
        float s = 0.f;
#pragma unroll
        for (int e = 0; e < 8; ++e) s += weight[((e * 32 + o) * 32 + c) * 27 + t];
        ((unsigned short*)(ws + WF_OFF))[i] = (unsigned short)bf16rne(s);
    } else if (i < 27904) {
        int k = i - 27648;
        int b = k >> 5, o = k & 31;
        float rs = 0.f, bs = 0.f;
#pragma unroll
        for (int e = 0; e < 8; ++e) { rs += rw[b * 8 + e]; bs += bias[e * 32 + o]; }
        ((float*)(ws + RWB_OFF))[k] = rs * bs;
        if (o == 0) ((float*)(ws + RWS_OFF))[b] = rs;
    }
}

// ---------------------------------------------------------------------------
// Cast+transpose: x fp32 [b][c][z][y][x] -> bf16 xT [b][z][y][x][c]
// One block per (b,z,y) row; LDS tile [32 c][68 x-padded] fp32.
// ---------------------------------------------------------------------------
__global__ __launch_bounds__(256) void condconv_cast(const float* __restrict__ x,
                                                     char* __restrict__ xT) {
    __shared__ float lds[32 * 68];
    const int tid = threadIdx.x;
    const int y = blockIdx.x, z = blockIdx.y, b = blockIdx.z;
    const float* src = x + (((size_t)(b * 32) * 16 + z) * 64 + y) * 64;  // c=0 row
#pragma unroll
    for (int it = 0; it < 2; ++it) {
        int s = tid + it * 256;          // 512 float4 slots = 32c x 16 xq
        int c = s >> 4, xq = (s & 15) * 4;
        float4 v = *(const float4*)(src + (size_t)c * 65536 + xq);
        *(float4*)&lds[c * 68 + xq] = v;
    }
    __syncthreads();
    const int x_ = tid >> 2, cq = tid & 3;   // x_ 0..63, cq = 8c-granule
    unsigned p[4];
#pragma unroll
    for (int jp = 0; jp < 4; ++jp) {
        float f0 = lds[(8 * cq + 2 * jp) * 68 + x_];
        float f1 = lds[(8 * cq + 2 * jp + 1) * 68 + x_];
        p[jp] = bf16rne(f0) | (bf16rne(f1) << 16);
    }
    *(uint4*)(xT + ((size_t)((b * 16 + z) * 64 + y)) * 4096 + x_ * 64 + cq * 16) =
        *(uint4*)p;
}

// ---------------------------------------------------------------------------
// Conv: implicit GEMM, bf16 MFMA 16x16x32.
//   D[o][x] += W[o][c] * xT[...][x+dx-1][c]   accumulated over 27 taps.
// Block = (b, z, 4 y-rows); 4 waves; wave w owns x-chunk [16w,16w+16), all 32 o.
// LDS x-tile: [3 z'][6 y'][66 x (halo)][32 c] bf16 = 76032 B.
// ---------------------------------------------------------------------------
__global__ __launch_bounds__(256) void condconv_mfma(
        const char* __restrict__ xT,
        const char* __restrict__ wf,     // ws + WF_OFF
        const float* __restrict__ rwbias,
        const float* __restrict__ rwsum,
        float* __restrict__ out) {
    __shared__ uint4 smem4[4752];        // 76032 B
    char* smem = (char*)smem4;

    const int tid  = threadIdx.x;
    const int wv   = tid >> 6;
    const int lane = tid & 63;
    const int n    = lane & 15;
    const int quad = lane >> 4;
    const int y0   = blockIdx.x * 4;
    const int z    = blockIdx.y;
    const int b    = blockIdx.z;
    const int xn   = wv * 16 + n;

    // zero halo columns (xi = 0 and 65) once
    if (tid < 144) {
        int row = tid >> 3, rem = tid & 7;
        int side = rem >> 2, c8 = rem & 3;
        *(uint4*)(smem + (row * 66 + side * 65) * 64 + c8 * 16) = make_uint4(0, 0, 0, 0);
    }

    // stage 18 (z',y') rows: 4 KB contiguous each from xT, zero OOB rows
    const char* srcbase = xT + (size_t)b * (16 * 64 * 4096);
#pragma unroll
    for (int row = 0; row < 18; ++row) {
        const int zp = row / 6, yp = row % 6;
        const int gz = z + zp - 1, gy = y0 + yp - 1;
        uint4 v = make_uint4(0, 0, 0, 0);
        if ((unsigned)gz < 16u && (unsigned)gy < 64u)
            v = *(const uint4*)(srcbase + ((size_t)gz * 64 + gy) * 4096 + tid * 16);
        *(uint4*)(smem + (row * 66 + 1) * 64 + tid * 16) = v;
    }
    __syncthreads();

    f32x4 acc[2][4] = {};                      // [o-tile][y-row]
    const char* wbase = wf + lane * 16;
    const char* base0 = smem + xn * 64 + quad * 16;

#pragma unroll
    for (int dz = 0; dz < 3; ++dz)
#pragma unroll
        for (int dy = 0; dy < 3; ++dy)
#pragma unroll
            for (int dx = 0; dx < 3; ++dx) {
                const int t = (dz * 3 + dy) * 3 + dx;
                short8 w0 = *(const short8*)(wbase + (t * 2 + 0) * 1024);
                short8 w1 = *(const short8*)(wbase + (t * 2 + 1) * 1024);
                const int off = ((dz * 6 + dy) * 66 + dx) * 64;
#pragma unroll
                for (int r = 0; r < 4; ++r) {
                    short8 xf = *(const short8*)(base0 + r * 4224 + off);
                    acc[0][r] = __builtin_amdgcn_mfma_f32_16x16x32_bf16(w0, xf, acc[0][r], 0, 0, 0);
                    acc[1][r] = __builtin_amdgcn_mfma_f32_16x16x32_bf16(w1, xf, acc[1][r], 0, 0, 0);
                }
            }

    // epilogue: out = rw_sum[b]*acc + rw_sum[b]*bias_sum[o]
    const float rwb = rwsum[b];
#pragma unroll
    for (int ot = 0; ot < 2; ++ot)
#pragma unroll
        for (int reg = 0; reg < 4; ++reg) {
            const int o = ot * 16 + quad * 4 + reg;   // D row = quad*4+reg
            const float bb = rwbias[b * 32 + o];
            const size_t obase = ((size_t)(b * 32 + o) * 16 + z) * 64;
#pragma unroll
            for (int r = 0; r < 4; ++r)
                out[(obase + y0 + r) * 64 + xn] = rwb * acc[ot][r][reg] + bb;
        }
}

// ---------------------------------------------------------------------------
extern "C" void kernel_launch(void* const* d_in, const int* in_sizes, int n_in,
                              void* d_out, int out_size, void* d_ws, size_t ws_size,
                              hipStream_t stream) {
    const float* x      = (const float*)d_in[0];  // [8,32,16,64,64]
    const float* rw     = (const float*)d_in[1];  // [8,8]
    const float* weight = (const float*)d_in[2];  // [8,32,32,3,3,3]
    const float* bias   = (const float*)d_in[3];  // [8,32]
    float* out = (float*)d_out;
    char*  ws  = (char*)d_ws;

    condconv_prep<<<109, 256, 0, stream>>>(rw, weight, bias, ws);
    condconv_cast<<<dim3(64, 16, 8), 256, 0, stream>>>(x, ws + XT_OFF);
    condconv_mfma<<<dim3(16, 16, 8), 256, 0, stream>>>(
        ws + XT_OFF, ws + WF_OFF,
        (const float*)(ws + RWB_OFF), (const float*)(ws + RWS_OFF), out);
}